// Round 11
// baseline (871.470 us; speedup 1.0000x reference)
//
#include <hip/hip_runtime.h>
#include <math.h>

// GARNN: graph-attention GRU, B=16, N=512, U=64, SEQ=12, HORIZON=12, all f32.
// R11 = R7 (XCD swizzle, 802us best) with ONE structural change: phaseB gather
// depth 16->12 + launch_bounds (512,6)->(512,8). Goal: phaseB VGPR <=64 -> 4
// blocks/CU -> all 1024 blocks resident (kills the 256-block tail round that
// only phaseB has; phaseA is already 4 blk/CU per R9's neutrality). Loop shape
// kept EXACTLY R7's load-group-then-FMA-group for-loop: R6/R10 proved any
// rotated/peeled restructure collapses codegen (VGPR 32 = serialized gather).
// cnt clamped to 120 so ceil(c/12)*12 <= 120 < CAP (P(c>120)~1e-20).

#define NB 16
#define NN 512
#define NU 64
#define CAP 128   // neighbor-list capacity; cnt clamped to 120 (see k_adj)
#define WPB 8     // waves (=nodes) per block

#define AS1 __attribute__((address_space(1)))
#define AS3 __attribute__((address_space(3)))

__device__ __forceinline__ void ld_lds16(float* lds_uniform, const float* g_perlane) {
#if __has_builtin(__builtin_amdgcn_global_load_lds)
  __builtin_amdgcn_global_load_lds((const AS1 unsigned int*)g_perlane,
                                   (AS3 unsigned int*)lds_uniform, 16, 0, 0);
#else
  int lane = threadIdx.x & 63;
  *(float4*)(lds_uniform + lane * 4) = *(const float4*)(g_perlane);
#endif
}

// Async-stage TB bytes of weights into sW. Wave w handles chunks c = w, w+8, ...
__device__ __forceinline__ void stage_weights(float* sW, const float* W, int TB,
                                              int w, int lane) {
  for (int c = w; c * 1024 < TB; c += WPB) {
    int off = c * 1024 + lane * 16;
    if (off < TB)
      ld_lds16((float*)((char*)sW + c * 1024), (const float*)((const char*)W + off));
  }
}

__device__ __forceinline__ float rlane(float v, int l) {
  return __int_as_float(__builtin_amdgcn_readlane(__float_as_int(v), l));
}
__device__ __forceinline__ int rlane_i(int v, int l) {
  return __builtin_amdgcn_readlane(v, l);
}
__device__ __forceinline__ float wave_max(float v) {
  #pragma unroll
  for (int s = 1; s < 64; s <<= 1) v = fmaxf(v, __shfl_xor(v, s));
  return v;
}
__device__ __forceinline__ float wave_sum(float v) {
  #pragma unroll
  for (int s = 1; s < 64; s <<= 1) v += __shfl_xor(v, s);
  return v;
}
__device__ __forceinline__ void wave_sum2(float& x, float& y) {
  #pragma unroll
  for (int s = 1; s < 64; s <<= 1) { x += __shfl_xor(x, s); y += __shfl_xor(y, s); }
}
__device__ __forceinline__ float fast_rcp(float x) {
#if __has_builtin(__builtin_amdgcn_rcpf)
  return __builtin_amdgcn_rcpf(x);
#else
  return 1.0f / x;
#endif
}
__device__ __forceinline__ float sigmoid_f(float x) {
  return fast_rcp(1.0f + __expf(-x));
}
__device__ __forceinline__ float tanh_f(float x) {
  return 1.0f - 2.0f * fast_rcp(__expf(2.0f * x) + 1.0f);
}

// XCD-aware decode: blockIdx%8 selects XCD (dispatch heuristic). XCD x owns
// batches {2x, 2x+1}. Bijective over 1024 blocks. Perf-only heuristic.
__device__ __forceinline__ void decode_block(int bx, int w, int& b, int& i) {
  int x = bx & 7, k = bx >> 3;
  b = (x << 1) | (k >> 6);
  i = ((k & 63) << 3) | w;
}

// Neighbor lists: mask[i][j] = adj[i][j] > 0.9 || i == j, ascending j.
// cnt clamped to 120 (stride-12 gather: ceil(c/12)*12 <= 120 < CAP). Clamp has
// identical semantics to CAP truncation; P(Bin(511,~0.1) > 120) ~ 1e-20.
// Pad [cnt, CAP) with j=i so gather loops run unpredicated (p=0 there).
__global__ __launch_bounds__(64) void k_adj(const float* __restrict__ adj,
                                            int* __restrict__ cnt,
                                            int* __restrict__ idx) {
  int i = blockIdx.x;
  int l = threadIdx.x;
  int base = 0;
  #pragma unroll
  for (int c = 0; c < 8; ++c) {
    int j = c * 64 + l;
    bool pred = (adj[i * NN + j] > 0.9f) || (j == i);
    unsigned long long m = __ballot(pred);
    int pos = base + __popcll(m & ((1ull << l) - 1ull));
    if (pred && pos < 120) idx[i * CAP + pos] = j;
    base += __popcll(m);
  }
  int total = base > 120 ? 120 : base;
  for (int p = total + l; p < CAP; p += 64) idx[i * CAP + p] = i;  // pad
  if (l == 0) cnt[i] = total;
}

// Phase B: ru-attention -> r,u ; write u; h_c = [x, r*h] @ W_c; src_c/dst_c.
// (512,8): depth-12 gather (hv[12] = 24 VGPR) targets <=64 VGPR -> 4 blk/CU,
// single-round residency for all 1024 blocks.
template <int DIN>
__global__ __launch_bounds__(512, 8) void k_phaseB(
    const int* __restrict__ cnt, const int* __restrict__ idx,
    const float* __restrict__ h_ru, const float* __restrict__ src_ru,
    const float* __restrict__ dst_ru, const float* __restrict__ b_ru,
    const float* __restrict__ h, const float* __restrict__ x_ptr,
    const float* __restrict__ W_c, const float* __restrict__ a_c,
    float* __restrict__ h_c, float* __restrict__ src_c,
    float* __restrict__ dst_c, float* __restrict__ u_buf) {
  constexpr int TB = (DIN + NU) * NU * 4;
  __shared__ float sW[(DIN + NU) * NU];
  __shared__ float sh[WPB * NU];    // per-wave r*h broadcast
  const int tid = threadIdx.x;
  const int w = tid >> 6, lane = tid & 63;

  stage_weights(sW, W_c, TB, w, lane);   // async; drained at the barrier below

  int b, i;
  decode_block(blockIdx.x, w, b, i);
  const int base_bi = (b << 9) + i;
  const float* __restrict__ hrb = h_ru + ((size_t)b << 16);
  const float* __restrict__ drb = dst_ru + (b << 9);

  const int c_ = cnt[i];
  const float si = src_ru[base_bi];
  const int j0 = idx[(i << 7) + lane];
  const int j1 = idx[(i << 7) + 64 + lane];
  float e0 = -1e30f, e1 = -1e30f;
  if (lane < c_)      { float t = si + drb[j0]; e0 = t >= 0.f ? t : 0.2f * t; }
  if (lane + 64 < c_) { float t = si + drb[j1]; e1 = t >= 0.f ? t : 0.2f * t; }
  float m = wave_max(fmaxf(e0, e1));
  float p0 = (lane < c_) ? __expf(e0 - m) : 0.f;
  float p1 = (lane + 64 < c_) ? __expf(e1 - m) : 0.f;
  float inv = fast_rcp(wave_sum(p0 + p1));
  p0 *= inv; p1 *= inv;

  // aggregation: ru[g] over neighbors, g = 2*lane, 2*lane+1.
  // 12-deep register prefetch, R7 loop shape (load group, then FMA group).
  const int g0 = lane << 1;
  float A0 = 0.f, A1 = 0.f, B0 = 0.f, B1 = 0.f;
  const int cc = ((c_ + 11) / 12) * 12;   // c_ <= 120 -> cc <= 120 < CAP
  for (int base = 0; base < cc; base += 12) {
    float2 hv[12];
    #pragma unroll
    for (int q = 0; q < 12; ++q) {
      int jj = base + q;
      int sl = jj & 63;
      int j = (jj < 64) ? rlane_i(j0, sl) : rlane_i(j1, sl);
      hv[q] = *(const float2*)(hrb + (j << 7) + g0);
    }
    #pragma unroll
    for (int q = 0; q < 12; ++q) {
      int jj = base + q;
      int sl = jj & 63;
      float pv = (jj < 64) ? rlane(p0, sl) : rlane(p1, sl);
      if (q & 1) { B0 = fmaf(pv, hv[q].x, B0); B1 = fmaf(pv, hv[q].y, B1); }
      else       { A0 = fmaf(pv, hv[q].x, A0); A1 = fmaf(pv, hv[q].y, A1); }
    }
  }
  A0 += B0; A1 += B1;

  const float2 br = *(const float2*)(b_ru + g0);
  const float ru0 = sigmoid_f(A0 + br.x);
  const float ru1 = sigmoid_f(A1 + br.y);

  // lanes 0..31: r (g<64) -> r*h into LDS; lanes 32..63: u -> global
  if (lane < 32) {
    float2 hh = *(const float2*)(h + ((size_t)base_bi << 6) + g0);
    *(float2*)&sh[(w << 6) + g0] = make_float2(ru0 * hh.x, ru1 * hh.y);
  } else {
    *(float2*)(u_buf + ((size_t)base_bi << 6) + (g0 - 64)) = make_float2(ru0, ru1);
  }

  __syncthreads();   // drains async weight stage + sh visibility

  // h_c GEMV over xc = [x, r*h]; output feature = lane
  float acc;
  if (DIN == 2) {
    float2 xv = *(const float2*)(x_ptr + ((size_t)base_bi << 1));
    acc = xv.x * sW[lane];
    acc = fmaf(xv.y, sW[NU + lane], acc);
  } else {
    acc = x_ptr[base_bi] * sW[lane];
  }
  const float* __restrict__ sWh = sW + DIN * NU;
  const float* shw = sh + (w << 6);
  #pragma unroll
  for (int f2 = 0; f2 < 32; ++f2) {
    float2 rv = *(const float2*)(shw + 2 * f2);   // b64 broadcast
    acc = fmaf(rv.x, sWh[(2 * f2) * NU + lane], acc);
    acc = fmaf(rv.y, sWh[(2 * f2 + 1) * NU + lane], acc);
  }
  h_c[((size_t)base_bi << 6) + lane] = acc;
  float s0 = acc * a_c[lane];
  float s1 = acc * a_c[NU + lane];
  wave_sum2(s0, s1);
  if (lane == 0) { src_c[base_bi] = s0; dst_c[base_bi] = s1; }
}

// Phase A: c-attention -> c; h_new = u*h + (1-u)*c (UPD) or 0 (init);
// OUT: proj -> out+y_buf; DIN_NEXT>0: next cell h_ru = [x_next, h_new] @ W_ru.
// Exactly R7's structure (for-loop depth 16, (512,6)).
template <int UPD, int DIN_NEXT, int XMODE, int OUT>
__global__ __launch_bounds__(512, 6) void k_phaseA(
    const int* __restrict__ cnt, const int* __restrict__ idx,
    const float* __restrict__ h_c, const float* __restrict__ src_c,
    const float* __restrict__ dst_c, const float* __restrict__ b_c,
    const float* __restrict__ u_buf, float* __restrict__ h,
    const float* __restrict__ proj_W, const float* __restrict__ proj_b,
    float* __restrict__ out_slice, float* __restrict__ y_buf,
    const float* __restrict__ x_ptr,
    const float* __restrict__ W_ru, const float* __restrict__ a_ru,
    float* __restrict__ h_ru, float* __restrict__ src_ru,
    float* __restrict__ dst_ru) {
  constexpr int SWN = (DIN_NEXT > 0) ? (DIN_NEXT + NU) * 128 : 1;
  constexpr int TB = (DIN_NEXT > 0) ? SWN * 4 : 0;
  __shared__ float sW[SWN];
  __shared__ float sh[WPB * NU];
  const int tid = threadIdx.x;
  const int w = tid >> 6, lane = tid & 63;

  if (DIN_NEXT > 0) stage_weights(sW, W_ru, TB, w, lane);  // async

  int b, i;
  decode_block(blockIdx.x, w, b, i);
  const int base_bi = (b << 9) + i;

  float hn = 0.f;
  if (UPD) {
    const float* __restrict__ hcb = h_c + ((size_t)b << 15);
    const float* __restrict__ dcb = dst_c + (b << 9);
    const int c_ = cnt[i];
    const float si = src_c[base_bi];
    const int j0 = idx[(i << 7) + lane];
    const int j1 = idx[(i << 7) + 64 + lane];
    float e0 = -1e30f, e1 = -1e30f;
    if (lane < c_)      { float t = si + dcb[j0]; e0 = t >= 0.f ? t : 0.2f * t; }
    if (lane + 64 < c_) { float t = si + dcb[j1]; e1 = t >= 0.f ? t : 0.2f * t; }
    float m = wave_max(fmaxf(e0, e1));
    float p0 = (lane < c_) ? __expf(e0 - m) : 0.f;
    float p1 = (lane + 64 < c_) ? __expf(e1 - m) : 0.f;
    float inv = fast_rcp(wave_sum(p0 + p1));
    p0 *= inv; p1 *= inv;

    float A = 0.f, Bacc = 0.f;
    const int cc = (c_ + 15) & ~15;
    for (int base = 0; base < cc; base += 16) {
      float hv[16];
      #pragma unroll
      for (int q = 0; q < 16; ++q) {
        int jj = base + q;
        int sl = jj & 63;
        int j = (jj < 64) ? rlane_i(j0, sl) : rlane_i(j1, sl);
        hv[q] = hcb[(j << 6) + lane];
      }
      #pragma unroll
      for (int q = 0; q < 16; ++q) {
        int jj = base + q;
        int sl = jj & 63;
        float pv = (jj < 64) ? rlane(p0, sl) : rlane(p1, sl);
        if (q & 1) Bacc = fmaf(pv, hv[q], Bacc);
        else       A = fmaf(pv, hv[q], A);
      }
    }
    A += Bacc;
    const float cc_ = tanh_f(A + b_c[lane]);
    const float u = u_buf[((size_t)base_bi << 6) + lane];
    const float ho = h[((size_t)base_bi << 6) + lane];
    hn = fmaf(u, ho - cc_, cc_);   // u*ho + (1-u)*cc
  }
  h[((size_t)base_bi << 6) + lane] = hn;
  sh[(w << 6) + lane] = hn;        // wave-private broadcast buffer

  float y = 0.f;
  if (OUT) {
    float t = wave_sum(hn * proj_W[lane]);
    y = t + proj_b[0];
    if (lane == 0) { out_slice[base_bi] = y; y_buf[base_bi] = y; }
  }

  if (DIN_NEXT > 0) {
    __syncthreads();   // drains async weight stage; sh written above
    const int g0 = lane << 1;
    float a0, a1;
    if (XMODE == 0) {
      if (DIN_NEXT == 2) {
        float2 xv = *(const float2*)(x_ptr + ((size_t)base_bi << 1));
        a0 = xv.x * sW[g0];
        a1 = xv.x * sW[g0 + 1];
        a0 = fmaf(xv.y, sW[128 + g0], a0);
        a1 = fmaf(xv.y, sW[128 + g0 + 1], a1);
      } else {
        float xv = x_ptr[base_bi];
        a0 = xv * sW[g0]; a1 = xv * sW[g0 + 1];
      }
    } else if (XMODE == 2) {
      a0 = y * sW[g0]; a1 = y * sW[g0 + 1];
    } else {  // XMODE==1: decoder GO token (zeros)
      a0 = 0.f; a1 = 0.f;
    }
    const float* __restrict__ sWh = sW + DIN_NEXT * 128;
    const float* shw = sh + (w << 6);
    #pragma unroll
    for (int f2 = 0; f2 < 32; ++f2) {
      float2 hp = *(const float2*)(shw + 2 * f2);          // b64 broadcast
      float2 w0 = *(const float2*)(sWh + (2 * f2) * 128 + g0);
      float2 w1 = *(const float2*)(sWh + (2 * f2 + 1) * 128 + g0);
      a0 = fmaf(hp.x, w0.x, a0); a1 = fmaf(hp.x, w0.y, a1);
      a0 = fmaf(hp.y, w1.x, a0); a1 = fmaf(hp.y, w1.y, a1);
    }
    *(float2*)(h_ru + ((size_t)base_bi << 7) + g0) = make_float2(a0, a1);
    const float2 ar0 = *(const float2*)(a_ru + g0);
    const float2 ar1 = *(const float2*)(a_ru + 128 + g0);
    float s0 = a0 * ar0.x + a1 * ar0.y;
    float s1 = a0 * ar1.x + a1 * ar1.y;
    wave_sum2(s0, s1);
    if (lane == 0) { src_ru[base_bi] = s0; dst_ru[base_bi] = s1; }
  }
}

extern "C" void kernel_launch(void* const* d_in, const int* in_sizes, int n_in,
                              void* d_out, int out_size, void* d_ws, size_t ws_size,
                              hipStream_t stream) {
  (void)in_sizes; (void)n_in; (void)out_size; (void)ws_size;
  const float* inputs   = (const float*)d_in[0];
  const float* adj      = (const float*)d_in[1];
  const float* enc_W_ru = (const float*)d_in[2];
  const float* enc_a_ru = (const float*)d_in[3];
  const float* enc_b_ru = (const float*)d_in[4];
  const float* enc_W_c  = (const float*)d_in[5];
  const float* enc_a_c  = (const float*)d_in[6];
  const float* enc_b_c  = (const float*)d_in[7];
  const float* dec_W_ru = (const float*)d_in[8];
  const float* dec_a_ru = (const float*)d_in[9];
  const float* dec_b_ru = (const float*)d_in[10];
  const float* dec_W_c  = (const float*)d_in[11];
  const float* dec_a_c  = (const float*)d_in[12];
  const float* dec_b_c  = (const float*)d_in[13];
  const float* proj_W   = (const float*)d_in[14];
  const float* proj_b   = (const float*)d_in[15];
  float* out = (float*)d_out;

  char* ws = (char*)d_ws;
  int*   cnt    = (int*)ws;                    // 512*4        = 2048
  int*   idx    = (int*)(ws + 2048);           // 512*128*4    = 262144
  float* h      = (float*)(ws + 264192);       // 16*512*64*4  = 2097152
  float* h_ru   = (float*)(ws + 2361344);      // 16*512*128*4 = 4194304
  float* src_ru = (float*)(ws + 6555648);      // 32768
  float* dst_ru = (float*)(ws + 6588416);      // 32768
  float* h_c    = (float*)(ws + 6621184);      // 2097152
  float* src_c  = (float*)(ws + 8718336);      // 32768
  float* dst_c  = (float*)(ws + 8751104);      // 32768
  float* u_buf  = (float*)(ws + 8783872);      // 2097152
  float* y_buf  = (float*)(ws + 10881024);     // 32768 (end 10913792)

  hipMemsetAsync(y_buf, 0, NB * NN * sizeof(float), stream);
  k_adj<<<NN, 64, 0, stream>>>(adj, cnt, idx);

  const int GRID = (NB * NN) / WPB;  // 1024 blocks, 8 waves/block, 1 node/wave

  // init: h = 0, compute h_ru(x_0) with encoder weights
  k_phaseA<0, 2, 0, 0><<<GRID, 512, 0, stream>>>(cnt, idx, h_c, src_c, dst_c,
      enc_b_c, u_buf, h, proj_W, proj_b, nullptr, y_buf,
      inputs, enc_W_ru, enc_a_ru, h_ru, src_ru, dst_ru);

  for (int t = 0; t < 12; ++t) {
    k_phaseB<2><<<GRID, 512, 0, stream>>>(cnt, idx, h_ru, src_ru, dst_ru, enc_b_ru,
        h, inputs + (size_t)t * NB * NN * 2, enc_W_c, enc_a_c,
        h_c, src_c, dst_c, u_buf);
    if (t < 11)
      k_phaseA<1, 2, 0, 0><<<GRID, 512, 0, stream>>>(cnt, idx, h_c, src_c, dst_c,
          enc_b_c, u_buf, h, proj_W, proj_b, nullptr, y_buf,
          inputs + (size_t)(t + 1) * NB * NN * 2, enc_W_ru, enc_a_ru,
          h_ru, src_ru, dst_ru);
    else  // last encoder cell: prepare decoder cell 0 (x = GO = zeros)
      k_phaseA<1, 1, 1, 0><<<GRID, 512, 0, stream>>>(cnt, idx, h_c, src_c, dst_c,
          enc_b_c, u_buf, h, proj_W, proj_b, nullptr, y_buf,
          nullptr, dec_W_ru, dec_a_ru, h_ru, src_ru, dst_ru);
  }

  for (int k = 0; k < 12; ++k) {
    k_phaseB<1><<<GRID, 512, 0, stream>>>(cnt, idx, h_ru, src_ru, dst_ru, dec_b_ru,
        h, y_buf, dec_W_c, dec_a_c, h_c, src_c, dst_c, u_buf);
    if (k < 11)
      k_phaseA<1, 1, 2, 1><<<GRID, 512, 0, stream>>>(cnt, idx, h_c, src_c, dst_c,
          dec_b_c, u_buf, h, proj_W, proj_b, out + (size_t)k * NB * NN, y_buf,
          nullptr, dec_W_ru, dec_a_ru, h_ru, src_ru, dst_ru);
    else
      k_phaseA<1, 0, 1, 1><<<GRID, 512, 0, stream>>>(cnt, idx, h_c, src_c, dst_c,
          dec_b_c, u_buf, h, proj_W, proj_b, out + (size_t)k * NB * NN, y_buf,
          nullptr, dec_W_ru, dec_a_ru, h_ru, src_ru, dst_ru);
  }
}

// Round 12
// 856.827 us; speedup vs baseline: 1.0171x; 1.0171x over previous
//
#include <hip/hip_runtime.h>
#include <math.h>

// GARNN: graph-attention GRU, B=16, N=512, U=64, SEQ=12, HORIZON=12, all f32.
// R12 = R7 (802us best: XCD swizzle, depth-16 gather, (512,6)) with phaseA's
// UPD dispatches replaced by k_phaseA2: LDS-staged gather. 256 blocks (1/CU,
// 138KB LDS), each stages h_c[batch] (128KB) + dst_c (2KB) once, then 8 waves
// x 4 nodes gather from LDS (~6cy) instead of L2 (~300cy) -- kills the exposed
// latency chain that occupancy couldn't hide. LDS buffer reused for W_ru after
// a barrier. phaseB unchanged (h_ru slice = 256KB, doesn't fit LDS).

#define NB 16
#define NN 512
#define NU 64
#define CAP 128   // neighbor-list capacity (Bin(511,0.1) max << 128)
#define WPB 8     // waves per block

#define AS1 __attribute__((address_space(1)))
#define AS3 __attribute__((address_space(3)))

__device__ __forceinline__ void ld_lds16(float* lds_uniform, const float* g_perlane) {
#if __has_builtin(__builtin_amdgcn_global_load_lds)
  __builtin_amdgcn_global_load_lds((const AS1 unsigned int*)g_perlane,
                                   (AS3 unsigned int*)lds_uniform, 16, 0, 0);
#else
  int lane = threadIdx.x & 63;
  *(float4*)(lds_uniform + lane * 4) = *(const float4*)(g_perlane);
#endif
}

// Async-stage TB bytes into LDS; wave w handles 1KB chunks c = w, w+8, ...
__device__ __forceinline__ void stage_lds(float* dst, const float* src, int TB,
                                          int w, int lane) {
  for (int c = w; c * 1024 < TB; c += WPB) {
    int off = c * 1024 + lane * 16;
    if (off < TB)
      ld_lds16((float*)((char*)dst + c * 1024), (const float*)((const char*)src + off));
  }
}

__device__ __forceinline__ float rlane(float v, int l) {
  return __int_as_float(__builtin_amdgcn_readlane(__float_as_int(v), l));
}
__device__ __forceinline__ int rlane_i(int v, int l) {
  return __builtin_amdgcn_readlane(v, l);
}
__device__ __forceinline__ float wave_max(float v) {
  #pragma unroll
  for (int s = 1; s < 64; s <<= 1) v = fmaxf(v, __shfl_xor(v, s));
  return v;
}
__device__ __forceinline__ float wave_sum(float v) {
  #pragma unroll
  for (int s = 1; s < 64; s <<= 1) v += __shfl_xor(v, s);
  return v;
}
__device__ __forceinline__ void wave_sum2(float& x, float& y) {
  #pragma unroll
  for (int s = 1; s < 64; s <<= 1) { x += __shfl_xor(x, s); y += __shfl_xor(y, s); }
}
__device__ __forceinline__ float fast_rcp(float x) {
#if __has_builtin(__builtin_amdgcn_rcpf)
  return __builtin_amdgcn_rcpf(x);
#else
  return 1.0f / x;
#endif
}
__device__ __forceinline__ float sigmoid_f(float x) {
  return fast_rcp(1.0f + __expf(-x));
}
__device__ __forceinline__ float tanh_f(float x) {
  return 1.0f - 2.0f * fast_rcp(__expf(2.0f * x) + 1.0f);
}

// XCD-aware decode for 1024-block kernels (phaseB, init): XCD x owns batches
// {2x, 2x+1}. Bijective. Perf-only heuristic.
__device__ __forceinline__ void decode_block(int bx, int w, int& b, int& i) {
  int x = bx & 7, k = bx >> 3;
  b = (x << 1) | (k >> 6);
  i = ((k & 63) << 3) | w;
}

// Neighbor lists: mask[i][j] = adj[i][j] > 0.9 || i == j, ascending j.
// Pad tail [cnt, CAP) with j=i so gather loops run unpredicated (p=0 there).
__global__ __launch_bounds__(64) void k_adj(const float* __restrict__ adj,
                                            int* __restrict__ cnt,
                                            int* __restrict__ idx) {
  int i = blockIdx.x;
  int l = threadIdx.x;
  int base = 0;
  #pragma unroll
  for (int c = 0; c < 8; ++c) {
    int j = c * 64 + l;
    bool pred = (adj[i * NN + j] > 0.9f) || (j == i);
    unsigned long long m = __ballot(pred);
    int pos = base + __popcll(m & ((1ull << l) - 1ull));
    if (pred && pos < CAP) idx[i * CAP + pos] = j;
    base += __popcll(m);
  }
  int total = base > CAP ? CAP : base;
  for (int p = total + l; p < CAP; p += 64) idx[i * CAP + p] = i;  // pad
  if (l == 0) cnt[i] = total;
}

// Phase B: ru-attention -> r,u ; write u; h_c = [x, r*h] @ W_c; src_c/dst_c.
// EXACT R7 structure (depth-16 gather, (512,6)).
template <int DIN>
__global__ __launch_bounds__(512, 6) void k_phaseB(
    const int* __restrict__ cnt, const int* __restrict__ idx,
    const float* __restrict__ h_ru, const float* __restrict__ src_ru,
    const float* __restrict__ dst_ru, const float* __restrict__ b_ru,
    const float* __restrict__ h, const float* __restrict__ x_ptr,
    const float* __restrict__ W_c, const float* __restrict__ a_c,
    float* __restrict__ h_c, float* __restrict__ src_c,
    float* __restrict__ dst_c, float* __restrict__ u_buf) {
  constexpr int TB = (DIN + NU) * NU * 4;
  __shared__ float sW[(DIN + NU) * NU];
  __shared__ float sh[WPB * NU];    // per-wave r*h broadcast
  const int tid = threadIdx.x;
  const int w = tid >> 6, lane = tid & 63;

  stage_lds(sW, W_c, TB, w, lane);   // async; drained at the barrier below

  int b, i;
  decode_block(blockIdx.x, w, b, i);
  const int base_bi = (b << 9) + i;
  const float* __restrict__ hrb = h_ru + ((size_t)b << 16);
  const float* __restrict__ drb = dst_ru + (b << 9);

  const int c_ = cnt[i];
  const float si = src_ru[base_bi];
  const int j0 = idx[(i << 7) + lane];
  const int j1 = idx[(i << 7) + 64 + lane];
  float e0 = -1e30f, e1 = -1e30f;
  if (lane < c_)      { float t = si + drb[j0]; e0 = t >= 0.f ? t : 0.2f * t; }
  if (lane + 64 < c_) { float t = si + drb[j1]; e1 = t >= 0.f ? t : 0.2f * t; }
  float m = wave_max(fmaxf(e0, e1));
  float p0 = (lane < c_) ? __expf(e0 - m) : 0.f;
  float p1 = (lane + 64 < c_) ? __expf(e1 - m) : 0.f;
  float inv = fast_rcp(wave_sum(p0 + p1));
  p0 *= inv; p1 *= inv;

  const int g0 = lane << 1;
  float A0 = 0.f, A1 = 0.f, B0 = 0.f, B1 = 0.f;
  const int cc = (c_ + 15) & ~15;
  for (int base = 0; base < cc; base += 16) {
    float2 hv[16];
    #pragma unroll
    for (int q = 0; q < 16; ++q) {
      int jj = base + q;
      int sl = jj & 63;
      int j = (jj < 64) ? rlane_i(j0, sl) : rlane_i(j1, sl);
      hv[q] = *(const float2*)(hrb + (j << 7) + g0);
    }
    #pragma unroll
    for (int q = 0; q < 16; ++q) {
      int jj = base + q;
      int sl = jj & 63;
      float pv = (jj < 64) ? rlane(p0, sl) : rlane(p1, sl);
      if (q & 1) { B0 = fmaf(pv, hv[q].x, B0); B1 = fmaf(pv, hv[q].y, B1); }
      else       { A0 = fmaf(pv, hv[q].x, A0); A1 = fmaf(pv, hv[q].y, A1); }
    }
  }
  A0 += B0; A1 += B1;

  const float2 br = *(const float2*)(b_ru + g0);
  const float ru0 = sigmoid_f(A0 + br.x);
  const float ru1 = sigmoid_f(A1 + br.y);

  if (lane < 32) {
    float2 hh = *(const float2*)(h + ((size_t)base_bi << 6) + g0);
    *(float2*)&sh[(w << 6) + g0] = make_float2(ru0 * hh.x, ru1 * hh.y);
  } else {
    *(float2*)(u_buf + ((size_t)base_bi << 6) + (g0 - 64)) = make_float2(ru0, ru1);
  }

  __syncthreads();   // drains async weight stage + sh visibility

  float acc;
  if (DIN == 2) {
    float2 xv = *(const float2*)(x_ptr + ((size_t)base_bi << 1));
    acc = xv.x * sW[lane];
    acc = fmaf(xv.y, sW[NU + lane], acc);
  } else {
    acc = x_ptr[base_bi] * sW[lane];
  }
  const float* __restrict__ sWh = sW + DIN * NU;
  const float* shw = sh + (w << 6);
  #pragma unroll
  for (int f2 = 0; f2 < 32; ++f2) {
    float2 rv = *(const float2*)(shw + 2 * f2);
    acc = fmaf(rv.x, sWh[(2 * f2) * NU + lane], acc);
    acc = fmaf(rv.y, sWh[(2 * f2 + 1) * NU + lane], acc);
  }
  h_c[((size_t)base_bi << 6) + lane] = acc;
  float s0 = acc * a_c[lane];
  float s1 = acc * a_c[NU + lane];
  wave_sum2(s0, s1);
  if (lane == 0) { src_c[base_bi] = s0; dst_c[base_bi] = s1; }
}

// Init-only phaseA (UPD=0): h=0, h_ru = [x_0, 0] @ enc_W_ru. R7 structure.
__global__ __launch_bounds__(512, 6) void k_init(
    float* __restrict__ h, const float* __restrict__ x_ptr,
    const float* __restrict__ W_ru, const float* __restrict__ a_ru,
    float* __restrict__ h_ru, float* __restrict__ src_ru,
    float* __restrict__ dst_ru) {
  __shared__ float sW[66 * 128];
  __shared__ float sh[WPB * NU];
  const int tid = threadIdx.x;
  const int w = tid >> 6, lane = tid & 63;
  stage_lds(sW, W_ru, 66 * 128 * 4, w, lane);

  int b, i;
  decode_block(blockIdx.x, w, b, i);
  const int base_bi = (b << 9) + i;

  h[((size_t)base_bi << 6) + lane] = 0.f;
  sh[(w << 6) + lane] = 0.f;
  __syncthreads();

  const int g0 = lane << 1;
  float2 xv = *(const float2*)(x_ptr + ((size_t)base_bi << 1));
  float a0 = xv.x * sW[g0];
  float a1 = xv.x * sW[g0 + 1];
  a0 = fmaf(xv.y, sW[128 + g0], a0);
  a1 = fmaf(xv.y, sW[128 + g0 + 1], a1);
  // h term is zero (h=0) -> skip the f-loop entirely (bit-identical: +0 terms)
  *(float2*)(h_ru + ((size_t)base_bi << 7) + g0) = make_float2(a0, a1);
  const float2 ar0 = *(const float2*)(a_ru + g0);
  const float2 ar1 = *(const float2*)(a_ru + 128 + g0);
  float s0 = a0 * ar0.x + a1 * ar0.y;
  float s1 = a0 * ar1.x + a1 * ar1.y;
  wave_sum2(s0, s1);
  if (lane == 0) { src_ru[base_bi] = s0; dst_ru[base_bi] = s1; }
}

// Phase A2: LDS-staged c-attention. 256 blocks (1/CU), 8 waves, 4 nodes/wave.
// Stage h_c[b] (128KB) + dst_c[b] (2KB) once; gathers hit LDS. After attention
// the 128KB buffer is reused for W_ru (34KB). Math identical to R7's phaseA.
template <int DIN_NEXT, int XMODE, int OUT>
__global__ __launch_bounds__(512, 2) void k_phaseA2(
    const int* __restrict__ cnt, const int* __restrict__ idx,
    const float* __restrict__ h_c, const float* __restrict__ src_c,
    const float* __restrict__ dst_c, const float* __restrict__ b_c,
    const float* __restrict__ u_buf, float* __restrict__ h,
    const float* __restrict__ proj_W, const float* __restrict__ proj_b,
    float* __restrict__ out_slice, float* __restrict__ y_buf,
    const float* __restrict__ x_ptr,
    const float* __restrict__ W_ru, const float* __restrict__ a_ru,
    float* __restrict__ h_ru, float* __restrict__ src_ru,
    float* __restrict__ dst_ru) {
  __shared__ float lds_main[NN * NU];   // 128KB: h_c[b] slice, then W_ru
  __shared__ float sh[32 * NU];         // 8KB: hn per node slot
  __shared__ float sdst[NN];            // 2KB: dst_c[b]
  __shared__ float sy[32];              // per-node projected y
  const int tid = threadIdx.x;
  const int w = tid >> 6, lane = tid & 63;
  // decode: XCD x owns batches {2x, 2x+1}; 16 blocks per batch, 32 nodes each.
  const int b = ((blockIdx.x & 7) << 1) | ((blockIdx.x >> 3) >> 4);
  const int group = (blockIdx.x >> 3) & 15;

  stage_lds(lds_main, h_c + ((size_t)b << 15), NN * NU * 4, w, lane);
  if (w == 0) {  // 2KB = 2 chunks
    const char* s2 = (const char*)(dst_c + (b << 9));
    ld_lds16(sdst, (const float*)(s2 + lane * 16));
    ld_lds16(sdst + 256, (const float*)(s2 + 1024 + lane * 16));
  }
  __syncthreads();   // staged (barrier drains vmcnt)

  for (int n = 0; n < 4; ++n) {
    const int i = (group << 5) + (w << 2) + n;
    const int bi = (b << 9) + i;
    const float u_v = u_buf[((size_t)bi << 6) + lane];   // early: hidden under softmax
    const float ho  = h[((size_t)bi << 6) + lane];       // early
    const int c_ = cnt[i];
    const float si = src_c[bi];
    const int j0 = idx[(i << 7) + lane];
    const int j1 = idx[(i << 7) + 64 + lane];
    float e0 = -1e30f, e1 = -1e30f;
    if (lane < c_)      { float t = si + sdst[j0]; e0 = t >= 0.f ? t : 0.2f * t; }
    if (lane + 64 < c_) { float t = si + sdst[j1]; e1 = t >= 0.f ? t : 0.2f * t; }
    float m = wave_max(fmaxf(e0, e1));
    float p0 = (lane < c_) ? __expf(e0 - m) : 0.f;
    float p1 = (lane + 64 < c_) ? __expf(e1 - m) : 0.f;
    float inv = fast_rcp(wave_sum(p0 + p1));
    p0 *= inv; p1 *= inv;

    float A = 0.f, Bacc = 0.f;
    const int cc = (c_ + 15) & ~15;
    for (int base = 0; base < cc; base += 16) {
      float hv[16];
      #pragma unroll
      for (int q = 0; q < 16; ++q) {
        int jj = base + q;
        int sl = jj & 63;
        int j = (jj < 64) ? rlane_i(j0, sl) : rlane_i(j1, sl);
        hv[q] = lds_main[(j << 6) + lane];   // LDS gather, ~6cy throughput
      }
      #pragma unroll
      for (int q = 0; q < 16; ++q) {
        int jj = base + q;
        int sl = jj & 63;
        float pv = (jj < 64) ? rlane(p0, sl) : rlane(p1, sl);
        if (q & 1) Bacc = fmaf(pv, hv[q], Bacc);
        else       A = fmaf(pv, hv[q], A);
      }
    }
    A += Bacc;
    const float cc_ = tanh_f(A + b_c[lane]);
    const float hn = fmaf(u_v, ho - cc_, cc_);   // u*ho + (1-u)*cc
    h[((size_t)bi << 6) + lane] = hn;
    sh[((w << 2) + n) * NU + lane] = hn;

    if (OUT) {
      float t2 = wave_sum(hn * proj_W[lane]);
      float yv = t2 + proj_b[0];
      if (lane == 0) {
        out_slice[bi] = yv; y_buf[bi] = yv; sy[(w << 2) + n] = yv;
      }
    }
  }

  if (DIN_NEXT > 0) {
    __syncthreads();   // all h_c LDS reads done -> safe to overwrite
    stage_lds(lds_main, W_ru, (DIN_NEXT + NU) * 128 * 4, w, lane);
    __syncthreads();   // weights staged

    const int g0 = lane << 1;
    for (int n = 0; n < 4; ++n) {
      const int i = (group << 5) + (w << 2) + n;
      const int bi = (b << 9) + i;
      float a0, a1;
      if (XMODE == 0) {
        float2 xv = *(const float2*)(x_ptr + ((size_t)bi << 1));
        a0 = xv.x * lds_main[g0];
        a1 = xv.x * lds_main[g0 + 1];
        a0 = fmaf(xv.y, lds_main[128 + g0], a0);
        a1 = fmaf(xv.y, lds_main[128 + g0 + 1], a1);
      } else if (XMODE == 2) {
        float yv = sy[(w << 2) + n];
        a0 = yv * lds_main[g0]; a1 = yv * lds_main[g0 + 1];
      } else {  // GO token (zeros)
        a0 = 0.f; a1 = 0.f;
      }
      const float* sWh = lds_main + DIN_NEXT * 128;
      const float* shw = sh + ((w << 2) + n) * NU;
      #pragma unroll
      for (int f2 = 0; f2 < 32; ++f2) {
        float2 hp = *(const float2*)(shw + 2 * f2);
        float2 w0 = *(const float2*)(sWh + (2 * f2) * 128 + g0);
        float2 w1 = *(const float2*)(sWh + (2 * f2 + 1) * 128 + g0);
        a0 = fmaf(hp.x, w0.x, a0); a1 = fmaf(hp.x, w0.y, a1);
        a0 = fmaf(hp.y, w1.x, a0); a1 = fmaf(hp.y, w1.y, a1);
      }
      *(float2*)(h_ru + ((size_t)bi << 7) + g0) = make_float2(a0, a1);
      const float2 ar0 = *(const float2*)(a_ru + g0);
      const float2 ar1 = *(const float2*)(a_ru + 128 + g0);
      float s0 = a0 * ar0.x + a1 * ar0.y;
      float s1 = a0 * ar1.x + a1 * ar1.y;
      wave_sum2(s0, s1);
      if (lane == 0) { src_ru[bi] = s0; dst_ru[bi] = s1; }
    }
  }
}

extern "C" void kernel_launch(void* const* d_in, const int* in_sizes, int n_in,
                              void* d_out, int out_size, void* d_ws, size_t ws_size,
                              hipStream_t stream) {
  (void)in_sizes; (void)n_in; (void)out_size; (void)ws_size;
  const float* inputs   = (const float*)d_in[0];
  const float* adj      = (const float*)d_in[1];
  const float* enc_W_ru = (const float*)d_in[2];
  const float* enc_a_ru = (const float*)d_in[3];
  const float* enc_b_ru = (const float*)d_in[4];
  const float* enc_W_c  = (const float*)d_in[5];
  const float* enc_a_c  = (const float*)d_in[6];
  const float* enc_b_c  = (const float*)d_in[7];
  const float* dec_W_ru = (const float*)d_in[8];
  const float* dec_a_ru = (const float*)d_in[9];
  const float* dec_b_ru = (const float*)d_in[10];
  const float* dec_W_c  = (const float*)d_in[11];
  const float* dec_a_c  = (const float*)d_in[12];
  const float* dec_b_c  = (const float*)d_in[13];
  const float* proj_W   = (const float*)d_in[14];
  const float* proj_b   = (const float*)d_in[15];
  float* out = (float*)d_out;

  char* ws = (char*)d_ws;
  int*   cnt    = (int*)ws;                    // 512*4        = 2048
  int*   idx    = (int*)(ws + 2048);           // 512*128*4    = 262144
  float* h      = (float*)(ws + 264192);       // 16*512*64*4  = 2097152
  float* h_ru   = (float*)(ws + 2361344);      // 16*512*128*4 = 4194304
  float* src_ru = (float*)(ws + 6555648);      // 32768
  float* dst_ru = (float*)(ws + 6588416);      // 32768
  float* h_c    = (float*)(ws + 6621184);      // 2097152
  float* src_c  = (float*)(ws + 8718336);      // 32768
  float* dst_c  = (float*)(ws + 8751104);      // 32768
  float* u_buf  = (float*)(ws + 8783872);      // 2097152
  float* y_buf  = (float*)(ws + 10881024);     // 32768 (end 10913792)

  hipMemsetAsync(y_buf, 0, NB * NN * sizeof(float), stream);
  k_adj<<<NN, 64, 0, stream>>>(adj, cnt, idx);

  const int GRID = (NB * NN) / WPB;  // 1024 blocks (phaseB, init)
  const int GRID2 = 256;             // phaseA2: 1 block/CU

  // init: h = 0, compute h_ru(x_0) with encoder weights
  k_init<<<GRID, 512, 0, stream>>>(h, inputs, enc_W_ru, enc_a_ru,
                                   h_ru, src_ru, dst_ru);

  for (int t = 0; t < 12; ++t) {
    k_phaseB<2><<<GRID, 512, 0, stream>>>(cnt, idx, h_ru, src_ru, dst_ru, enc_b_ru,
        h, inputs + (size_t)t * NB * NN * 2, enc_W_c, enc_a_c,
        h_c, src_c, dst_c, u_buf);
    if (t < 11)
      k_phaseA2<2, 0, 0><<<GRID2, 512, 0, stream>>>(cnt, idx, h_c, src_c, dst_c,
          enc_b_c, u_buf, h, proj_W, proj_b, nullptr, y_buf,
          inputs + (size_t)(t + 1) * NB * NN * 2, enc_W_ru, enc_a_ru,
          h_ru, src_ru, dst_ru);
    else  // last encoder cell: prepare decoder cell 0 (x = GO = zeros)
      k_phaseA2<1, 1, 0><<<GRID2, 512, 0, stream>>>(cnt, idx, h_c, src_c, dst_c,
          enc_b_c, u_buf, h, proj_W, proj_b, nullptr, y_buf,
          nullptr, dec_W_ru, dec_a_ru, h_ru, src_ru, dst_ru);
  }

  for (int k = 0; k < 12; ++k) {
    k_phaseB<1><<<GRID, 512, 0, stream>>>(cnt, idx, h_ru, src_ru, dst_ru, dec_b_ru,
        h, y_buf, dec_W_c, dec_a_c, h_c, src_c, dst_c, u_buf);
    if (k < 11)
      k_phaseA2<1, 2, 1><<<GRID2, 512, 0, stream>>>(cnt, idx, h_c, src_c, dst_c,
          dec_b_c, u_buf, h, proj_W, proj_b, out + (size_t)k * NB * NN, y_buf,
          nullptr, dec_W_ru, dec_a_ru, h_ru, src_ru, dst_ru);
    else
      k_phaseA2<0, 1, 1><<<GRID2, 512, 0, stream>>>(cnt, idx, h_c, src_c, dst_c,
          dec_b_c, u_buf, h, proj_W, proj_b, out + (size_t)k * NB * NN, y_buf,
          nullptr, dec_W_ru, dec_a_ru, h_ru, src_ru, dst_ru);
  }
}

// Round 13
// 758.636 us; speedup vs baseline: 1.1487x; 1.1294x over previous
//
#include <hip/hip_runtime.h>
#include <math.h>

// GARNN: graph-attention GRU, B=16, N=512, U=64, SEQ=12, HORIZON=12, all f32.
// R13 = R7 (802us best: XCD swizzle, depth-16 gather, (512,6)) split into TWO
// INDEPENDENT batch halves (0-7, 8-15) on two forked streams (graph-capturable
// event fork/join). Halves share no data through the whole network, so stream
// B's dispatch ramp overlaps stream A's drain at every one of 25 slots --
// attacks the inter-dispatch bubbles that in-kernel knobs (R5/R6/R8/R10/R11/
// R12 all failed) cannot. Per-dispatch grid = 512 blocks; XCD decode gives
// each XCD 1 batch per half (2 total -> same 1.3MB L2 set as R7).
// Kernel math is byte-identical to R7 -> absmax must stay 1.525879e-05.

#define NB 16
#define NN 512
#define NU 64
#define CAP 128   // neighbor-list capacity (Bin(511,0.1) max << 128)
#define WPB 8     // waves (=nodes) per block

#define AS1 __attribute__((address_space(1)))
#define AS3 __attribute__((address_space(3)))

__device__ __forceinline__ void ld_lds16(float* lds_uniform, const float* g_perlane) {
#if __has_builtin(__builtin_amdgcn_global_load_lds)
  __builtin_amdgcn_global_load_lds((const AS1 unsigned int*)g_perlane,
                                   (AS3 unsigned int*)lds_uniform, 16, 0, 0);
#else
  int lane = threadIdx.x & 63;
  *(float4*)(lds_uniform + lane * 4) = *(const float4*)(g_perlane);
#endif
}

// Async-stage TB bytes of weights into sW. Wave w handles chunks c = w, w+8, ...
__device__ __forceinline__ void stage_weights(float* sW, const float* W, int TB,
                                              int w, int lane) {
  for (int c = w; c * 1024 < TB; c += WPB) {
    int off = c * 1024 + lane * 16;
    if (off < TB)
      ld_lds16((float*)((char*)sW + c * 1024), (const float*)((const char*)W + off));
  }
}

__device__ __forceinline__ float rlane(float v, int l) {
  return __int_as_float(__builtin_amdgcn_readlane(__float_as_int(v), l));
}
__device__ __forceinline__ int rlane_i(int v, int l) {
  return __builtin_amdgcn_readlane(v, l);
}
__device__ __forceinline__ float wave_max(float v) {
  #pragma unroll
  for (int s = 1; s < 64; s <<= 1) v = fmaxf(v, __shfl_xor(v, s));
  return v;
}
__device__ __forceinline__ float wave_sum(float v) {
  #pragma unroll
  for (int s = 1; s < 64; s <<= 1) v += __shfl_xor(v, s);
  return v;
}
__device__ __forceinline__ void wave_sum2(float& x, float& y) {
  #pragma unroll
  for (int s = 1; s < 64; s <<= 1) { x += __shfl_xor(x, s); y += __shfl_xor(y, s); }
}
__device__ __forceinline__ float fast_rcp(float x) {
#if __has_builtin(__builtin_amdgcn_rcpf)
  return __builtin_amdgcn_rcpf(x);
#else
  return 1.0f / x;
#endif
}
__device__ __forceinline__ float sigmoid_f(float x) {
  return fast_rcp(1.0f + __expf(-x));
}
__device__ __forceinline__ float tanh_f(float x) {
  return 1.0f - 2.0f * fast_rcp(__expf(2.0f * x) + 1.0f);
}

// Half-grid decode (512 blocks, 8 batches): XCD x = bx&7 owns batch bhalf+x;
// node i = (bx>>3)*8 + wave. Bijective per half. Perf-only heuristic.
__device__ __forceinline__ void decode_half(int bx, int w, int bhalf,
                                            int& b, int& i) {
  b = bhalf + (bx & 7);
  i = (((bx >> 3)) << 3) | w;
}

// Neighbor lists: mask[i][j] = adj[i][j] > 0.9 || i == j, ascending j.
// Pad tail [cnt, CAP) with j=i so gather loops run unpredicated (p=0 there).
__global__ __launch_bounds__(64) void k_adj(const float* __restrict__ adj,
                                            int* __restrict__ cnt,
                                            int* __restrict__ idx) {
  int i = blockIdx.x;
  int l = threadIdx.x;
  int base = 0;
  #pragma unroll
  for (int c = 0; c < 8; ++c) {
    int j = c * 64 + l;
    bool pred = (adj[i * NN + j] > 0.9f) || (j == i);
    unsigned long long m = __ballot(pred);
    int pos = base + __popcll(m & ((1ull << l) - 1ull));
    if (pred && pos < CAP) idx[i * CAP + pos] = j;
    base += __popcll(m);
  }
  int total = base > CAP ? CAP : base;
  for (int p = total + l; p < CAP; p += 64) idx[i * CAP + p] = i;  // pad
  if (l == 0) cnt[i] = total;
}

// Phase B: ru-attention -> r,u ; write u; h_c = [x, r*h] @ W_c; src_c/dst_c.
// EXACT R7 structure (depth-16 gather, (512,6)); bhalf selects batch half.
template <int DIN>
__global__ __launch_bounds__(512, 6) void k_phaseB(
    const int* __restrict__ cnt, const int* __restrict__ idx,
    const float* __restrict__ h_ru, const float* __restrict__ src_ru,
    const float* __restrict__ dst_ru, const float* __restrict__ b_ru,
    const float* __restrict__ h, const float* __restrict__ x_ptr,
    const float* __restrict__ W_c, const float* __restrict__ a_c,
    float* __restrict__ h_c, float* __restrict__ src_c,
    float* __restrict__ dst_c, float* __restrict__ u_buf, int bhalf) {
  constexpr int TB = (DIN + NU) * NU * 4;
  __shared__ float sW[(DIN + NU) * NU];
  __shared__ float sh[WPB * NU];    // per-wave r*h broadcast
  const int tid = threadIdx.x;
  const int w = tid >> 6, lane = tid & 63;

  stage_weights(sW, W_c, TB, w, lane);   // async; drained at the barrier below

  int b, i;
  decode_half(blockIdx.x, w, bhalf, b, i);
  const int base_bi = (b << 9) + i;
  const float* __restrict__ hrb = h_ru + ((size_t)b << 16);
  const float* __restrict__ drb = dst_ru + (b << 9);

  const int c_ = cnt[i];
  const float si = src_ru[base_bi];
  const int j0 = idx[(i << 7) + lane];
  const int j1 = idx[(i << 7) + 64 + lane];
  float e0 = -1e30f, e1 = -1e30f;
  if (lane < c_)      { float t = si + drb[j0]; e0 = t >= 0.f ? t : 0.2f * t; }
  if (lane + 64 < c_) { float t = si + drb[j1]; e1 = t >= 0.f ? t : 0.2f * t; }
  float m = wave_max(fmaxf(e0, e1));
  float p0 = (lane < c_) ? __expf(e0 - m) : 0.f;
  float p1 = (lane + 64 < c_) ? __expf(e1 - m) : 0.f;
  float inv = fast_rcp(wave_sum(p0 + p1));
  p0 *= inv; p1 *= inv;

  const int g0 = lane << 1;
  float A0 = 0.f, A1 = 0.f, B0 = 0.f, B1 = 0.f;
  const int cc = (c_ + 15) & ~15;
  for (int base = 0; base < cc; base += 16) {
    float2 hv[16];
    #pragma unroll
    for (int q = 0; q < 16; ++q) {
      int jj = base + q;
      int sl = jj & 63;
      int j = (jj < 64) ? rlane_i(j0, sl) : rlane_i(j1, sl);
      hv[q] = *(const float2*)(hrb + (j << 7) + g0);
    }
    #pragma unroll
    for (int q = 0; q < 16; ++q) {
      int jj = base + q;
      int sl = jj & 63;
      float pv = (jj < 64) ? rlane(p0, sl) : rlane(p1, sl);
      if (q & 1) { B0 = fmaf(pv, hv[q].x, B0); B1 = fmaf(pv, hv[q].y, B1); }
      else       { A0 = fmaf(pv, hv[q].x, A0); A1 = fmaf(pv, hv[q].y, A1); }
    }
  }
  A0 += B0; A1 += B1;

  const float2 br = *(const float2*)(b_ru + g0);
  const float ru0 = sigmoid_f(A0 + br.x);
  const float ru1 = sigmoid_f(A1 + br.y);

  if (lane < 32) {
    float2 hh = *(const float2*)(h + ((size_t)base_bi << 6) + g0);
    *(float2*)&sh[(w << 6) + g0] = make_float2(ru0 * hh.x, ru1 * hh.y);
  } else {
    *(float2*)(u_buf + ((size_t)base_bi << 6) + (g0 - 64)) = make_float2(ru0, ru1);
  }

  __syncthreads();   // drains async weight stage + sh visibility

  float acc;
  if (DIN == 2) {
    float2 xv = *(const float2*)(x_ptr + ((size_t)base_bi << 1));
    acc = xv.x * sW[lane];
    acc = fmaf(xv.y, sW[NU + lane], acc);
  } else {
    acc = x_ptr[base_bi] * sW[lane];
  }
  const float* __restrict__ sWh = sW + DIN * NU;
  const float* shw = sh + (w << 6);
  #pragma unroll
  for (int f2 = 0; f2 < 32; ++f2) {
    float2 rv = *(const float2*)(shw + 2 * f2);   // b64 broadcast
    acc = fmaf(rv.x, sWh[(2 * f2) * NU + lane], acc);
    acc = fmaf(rv.y, sWh[(2 * f2 + 1) * NU + lane], acc);
  }
  h_c[((size_t)base_bi << 6) + lane] = acc;
  float s0 = acc * a_c[lane];
  float s1 = acc * a_c[NU + lane];
  wave_sum2(s0, s1);
  if (lane == 0) { src_c[base_bi] = s0; dst_c[base_bi] = s1; }
}

// Phase A: c-attention -> c; h_new = u*h + (1-u)*c (UPD) or 0 (init);
// OUT: proj -> out+y_buf; DIN_NEXT>0: next cell h_ru = [x_next, h_new] @ W_ru.
// EXACT R7 structure; bhalf selects batch half.
template <int UPD, int DIN_NEXT, int XMODE, int OUT>
__global__ __launch_bounds__(512, 6) void k_phaseA(
    const int* __restrict__ cnt, const int* __restrict__ idx,
    const float* __restrict__ h_c, const float* __restrict__ src_c,
    const float* __restrict__ dst_c, const float* __restrict__ b_c,
    const float* __restrict__ u_buf, float* __restrict__ h,
    const float* __restrict__ proj_W, const float* __restrict__ proj_b,
    float* __restrict__ out_slice, float* __restrict__ y_buf,
    const float* __restrict__ x_ptr,
    const float* __restrict__ W_ru, const float* __restrict__ a_ru,
    float* __restrict__ h_ru, float* __restrict__ src_ru,
    float* __restrict__ dst_ru, int bhalf) {
  constexpr int SWN = (DIN_NEXT > 0) ? (DIN_NEXT + NU) * 128 : 1;
  constexpr int TB = (DIN_NEXT > 0) ? SWN * 4 : 0;
  __shared__ float sW[SWN];
  __shared__ float sh[WPB * NU];
  const int tid = threadIdx.x;
  const int w = tid >> 6, lane = tid & 63;

  if (DIN_NEXT > 0) stage_weights(sW, W_ru, TB, w, lane);  // async

  int b, i;
  decode_half(blockIdx.x, w, bhalf, b, i);
  const int base_bi = (b << 9) + i;

  float hn = 0.f;
  if (UPD) {
    const float* __restrict__ hcb = h_c + ((size_t)b << 15);
    const float* __restrict__ dcb = dst_c + (b << 9);
    const int c_ = cnt[i];
    const float si = src_c[base_bi];
    const int j0 = idx[(i << 7) + lane];
    const int j1 = idx[(i << 7) + 64 + lane];
    float e0 = -1e30f, e1 = -1e30f;
    if (lane < c_)      { float t = si + dcb[j0]; e0 = t >= 0.f ? t : 0.2f * t; }
    if (lane + 64 < c_) { float t = si + dcb[j1]; e1 = t >= 0.f ? t : 0.2f * t; }
    float m = wave_max(fmaxf(e0, e1));
    float p0 = (lane < c_) ? __expf(e0 - m) : 0.f;
    float p1 = (lane + 64 < c_) ? __expf(e1 - m) : 0.f;
    float inv = fast_rcp(wave_sum(p0 + p1));
    p0 *= inv; p1 *= inv;

    float A = 0.f, Bacc = 0.f;
    const int cc = (c_ + 15) & ~15;
    for (int base = 0; base < cc; base += 16) {
      float hv[16];
      #pragma unroll
      for (int q = 0; q < 16; ++q) {
        int jj = base + q;
        int sl = jj & 63;
        int j = (jj < 64) ? rlane_i(j0, sl) : rlane_i(j1, sl);
        hv[q] = hcb[(j << 6) + lane];
      }
      #pragma unroll
      for (int q = 0; q < 16; ++q) {
        int jj = base + q;
        int sl = jj & 63;
        float pv = (jj < 64) ? rlane(p0, sl) : rlane(p1, sl);
        if (q & 1) Bacc = fmaf(pv, hv[q], Bacc);
        else       A = fmaf(pv, hv[q], A);
      }
    }
    A += Bacc;
    const float cc_ = tanh_f(A + b_c[lane]);
    const float u = u_buf[((size_t)base_bi << 6) + lane];
    const float ho = h[((size_t)base_bi << 6) + lane];
    hn = fmaf(u, ho - cc_, cc_);   // u*ho + (1-u)*cc
  }
  h[((size_t)base_bi << 6) + lane] = hn;
  sh[(w << 6) + lane] = hn;        // wave-private broadcast buffer

  float y = 0.f;
  if (OUT) {
    float t = wave_sum(hn * proj_W[lane]);
    y = t + proj_b[0];
    if (lane == 0) { out_slice[base_bi] = y; y_buf[base_bi] = y; }
  }

  if (DIN_NEXT > 0) {
    __syncthreads();   // drains async weight stage; sh written above
    const int g0 = lane << 1;
    float a0, a1;
    if (XMODE == 0) {
      if (DIN_NEXT == 2) {
        float2 xv = *(const float2*)(x_ptr + ((size_t)base_bi << 1));
        a0 = xv.x * sW[g0];
        a1 = xv.x * sW[g0 + 1];
        a0 = fmaf(xv.y, sW[128 + g0], a0);
        a1 = fmaf(xv.y, sW[128 + g0 + 1], a1);
      } else {
        float xv = x_ptr[base_bi];
        a0 = xv * sW[g0]; a1 = xv * sW[g0 + 1];
      }
    } else if (XMODE == 2) {
      a0 = y * sW[g0]; a1 = y * sW[g0 + 1];
    } else {  // XMODE==1: decoder GO token (zeros)
      a0 = 0.f; a1 = 0.f;
    }
    const float* __restrict__ sWh = sW + DIN_NEXT * 128;
    const float* shw = sh + (w << 6);
    #pragma unroll
    for (int f2 = 0; f2 < 32; ++f2) {
      float2 hp = *(const float2*)(shw + 2 * f2);          // b64 broadcast
      float2 w0 = *(const float2*)(sWh + (2 * f2) * 128 + g0);
      float2 w1 = *(const float2*)(sWh + (2 * f2 + 1) * 128 + g0);
      a0 = fmaf(hp.x, w0.x, a0); a1 = fmaf(hp.x, w0.y, a1);
      a0 = fmaf(hp.y, w1.x, a0); a1 = fmaf(hp.y, w1.y, a1);
    }
    *(float2*)(h_ru + ((size_t)base_bi << 7) + g0) = make_float2(a0, a1);
    const float2 ar0 = *(const float2*)(a_ru + g0);
    const float2 ar1 = *(const float2*)(a_ru + 128 + g0);
    float s0 = a0 * ar0.x + a1 * ar0.y;
    float s1 = a0 * ar1.x + a1 * ar1.y;
    wave_sum2(s0, s1);
    if (lane == 0) { src_ru[base_bi] = s0; dst_ru[base_bi] = s1; }
  }
}

extern "C" void kernel_launch(void* const* d_in, const int* in_sizes, int n_in,
                              void* d_out, int out_size, void* d_ws, size_t ws_size,
                              hipStream_t stream) {
  (void)in_sizes; (void)n_in; (void)out_size; (void)ws_size;
  const float* inputs   = (const float*)d_in[0];
  const float* adj      = (const float*)d_in[1];
  const float* enc_W_ru = (const float*)d_in[2];
  const float* enc_a_ru = (const float*)d_in[3];
  const float* enc_b_ru = (const float*)d_in[4];
  const float* enc_W_c  = (const float*)d_in[5];
  const float* enc_a_c  = (const float*)d_in[6];
  const float* enc_b_c  = (const float*)d_in[7];
  const float* dec_W_ru = (const float*)d_in[8];
  const float* dec_a_ru = (const float*)d_in[9];
  const float* dec_b_ru = (const float*)d_in[10];
  const float* dec_W_c  = (const float*)d_in[11];
  const float* dec_a_c  = (const float*)d_in[12];
  const float* dec_b_c  = (const float*)d_in[13];
  const float* proj_W   = (const float*)d_in[14];
  const float* proj_b   = (const float*)d_in[15];
  float* out = (float*)d_out;

  char* ws = (char*)d_ws;
  int*   cnt    = (int*)ws;                    // 512*4        = 2048
  int*   idx    = (int*)(ws + 2048);           // 512*128*4    = 262144
  float* h      = (float*)(ws + 264192);       // 16*512*64*4  = 2097152
  float* h_ru   = (float*)(ws + 2361344);      // 16*512*128*4 = 4194304
  float* src_ru = (float*)(ws + 6555648);      // 32768
  float* dst_ru = (float*)(ws + 6588416);      // 32768
  float* h_c    = (float*)(ws + 6621184);      // 2097152
  float* src_c  = (float*)(ws + 8718336);      // 32768
  float* dst_c  = (float*)(ws + 8751104);      // 32768
  float* u_buf  = (float*)(ws + 8783872);      // 2097152
  float* y_buf  = (float*)(ws + 10881024);     // 32768 (end 10913792)

  // One-time side-stream + events (resources only; no work-affecting state).
  // Created on the first (non-captured) call; reused by the captured call.
  static hipStream_t s2 = nullptr;
  static hipEvent_t evFork = nullptr, evJoin = nullptr;
  if (s2 == nullptr) {
    hipStreamCreateWithFlags(&s2, hipStreamNonBlocking);
    hipEventCreateWithFlags(&evFork, hipEventDisableTiming);
    hipEventCreateWithFlags(&evJoin, hipEventDisableTiming);
  }

  hipMemsetAsync(y_buf, 0, NB * NN * sizeof(float), stream);
  k_adj<<<NN, 64, 0, stream>>>(adj, cnt, idx);

  // Fork: side stream joins the capture graph after k_adj.
  hipEventRecord(evFork, stream);
  hipStreamWaitEvent(s2, evFork, 0);

  const int GRID = (NB * NN) / (2 * WPB);  // 512 blocks per half-dispatch

  for (int half = 0; half < 2; ++half) {
    hipStream_t st = (half == 0) ? stream : s2;
    const int bh = half * 8;

    // init: h = 0, compute h_ru(x_0) with encoder weights
    k_phaseA<0, 2, 0, 0><<<GRID, 512, 0, st>>>(cnt, idx, h_c, src_c, dst_c,
        enc_b_c, u_buf, h, proj_W, proj_b, nullptr, y_buf,
        inputs, enc_W_ru, enc_a_ru, h_ru, src_ru, dst_ru, bh);

    for (int t = 0; t < 12; ++t) {
      k_phaseB<2><<<GRID, 512, 0, st>>>(cnt, idx, h_ru, src_ru, dst_ru, enc_b_ru,
          h, inputs + (size_t)t * NB * NN * 2, enc_W_c, enc_a_c,
          h_c, src_c, dst_c, u_buf, bh);
      if (t < 11)
        k_phaseA<1, 2, 0, 0><<<GRID, 512, 0, st>>>(cnt, idx, h_c, src_c, dst_c,
            enc_b_c, u_buf, h, proj_W, proj_b, nullptr, y_buf,
            inputs + (size_t)(t + 1) * NB * NN * 2, enc_W_ru, enc_a_ru,
            h_ru, src_ru, dst_ru, bh);
      else  // last encoder cell: prepare decoder cell 0 (x = GO = zeros)
        k_phaseA<1, 1, 1, 0><<<GRID, 512, 0, st>>>(cnt, idx, h_c, src_c, dst_c,
            enc_b_c, u_buf, h, proj_W, proj_b, nullptr, y_buf,
            nullptr, dec_W_ru, dec_a_ru, h_ru, src_ru, dst_ru, bh);
    }

    for (int k = 0; k < 12; ++k) {
      k_phaseB<1><<<GRID, 512, 0, st>>>(cnt, idx, h_ru, src_ru, dst_ru, dec_b_ru,
          h, y_buf, dec_W_c, dec_a_c, h_c, src_c, dst_c, u_buf, bh);
      if (k < 11)
        k_phaseA<1, 1, 2, 1><<<GRID, 512, 0, st>>>(cnt, idx, h_c, src_c, dst_c,
            dec_b_c, u_buf, h, proj_W, proj_b, out + (size_t)k * NB * NN, y_buf,
            nullptr, dec_W_ru, dec_a_ru, h_ru, src_ru, dst_ru, bh);
      else
        k_phaseA<1, 0, 1, 1><<<GRID, 512, 0, st>>>(cnt, idx, h_c, src_c, dst_c,
            dec_b_c, u_buf, h, proj_W, proj_b, out + (size_t)k * NB * NN, y_buf,
            nullptr, dec_W_ru, dec_a_ru, h_ru, src_ru, dst_ru, bh);
    }
  }

  // Join: main stream waits for the side half before kernel_launch returns.
  hipEventRecord(evJoin, s2);
  hipStreamWaitEvent(stream, evJoin, 0);
}